// Round 1
// baseline (240.277 us; speedup 1.0000x reference)
//
#include <hip/hip_runtime.h>

#define B_N 256
#define C_N 50000
#define D_N 512
#define ALPHA 0.5f

typedef float v4f __attribute__((ext_vector_type(4)));

#define ONEHOT4 (B_N * (C_N / 4))   // 3,200,000 float4s of onehot
#define CENT4   (C_N * (D_N / 4))   // 6,400,000 float4s of centers
#define TOTAL4  (ONEHOT4 + CENT4)   // 9,600,000 unified index space

// Dispatch 1: fused label-scan + centers->new_centers streaming copy.
// Unified grid-stride over [onehot float4s | centers float4s] so one
// BW-bound kernel covers all 256 MB of mandatory traffic. 2048 blocks x 256
// threads = 8192 waves = 32 waves/CU (max occupancy at this VGPR count).
// Labels: each one-hot row has exactly one 1.0, so exactly one (i,k) lane
// writes labels[b] -- no atomics, no counts, no memset needed.
__global__ __launch_bounds__(256) void scan_copy(
        const float* __restrict__ onehot,
        const v4f* __restrict__ centers4,
        v4f* __restrict__ newc4,
        int* __restrict__ labels) {
    const v4f* oh4 = (const v4f*)onehot;
    const int stride = gridDim.x * 256;
    for (int i = blockIdx.x * 256 + threadIdx.x; i < TOTAL4; i += stride) {
        if (i < ONEHOT4) {
            v4f v = __builtin_nontemporal_load(oh4 + i);  // streamed, never reused
            if (v[0] != 0.f || v[1] != 0.f || v[2] != 0.f || v[3] != 0.f) {
                int base = i * 4;
#pragma unroll
                for (int k = 0; k < 4; ++k) {
                    if (v[k] != 0.f) {
                        int g = base + k;
                        int b = g / C_N;          // rare path: magic-mul div
                        labels[b] = g - b * C_N;  // exactly one writer per b
                    }
                }
            }
        } else {
            int j = i - ONEHOT4;
            // untouched rows (49744+ of 50000) are final; touched rows get
            // overwritten by the fixup half of `finish` afterwards.
            __builtin_nontemporal_store(__builtin_nontemporal_load(centers4 + j),
                                        newc4 + j);
        }
    }
}

// Dispatch 2: blocks 0..255 compute result[b] = ||x_b - centers[label_b]||^2;
// blocks 256..511 rewrite the <=256 touched new_centers rows:
//   new[c] = centers[c]*(1 - a*n/(n+1)) + (a/(n+1)) * sum_{label_b=c} x[b]
// Dedup across duplicate labels via first-occurrence scan of the LDS-resident
// 1 KB label list.
__global__ __launch_bounds__(128) void finish(
        const float* __restrict__ x,
        const float* __restrict__ centers,
        const int* __restrict__ labels,
        float* __restrict__ result,
        float* __restrict__ newc) {
    __shared__ int lab[B_N];
    __shared__ float ws[2];
    int t = threadIdx.x;                         // 0..127, one float4 per thread
    lab[t] = labels[t];
    lab[t + 128] = labels[t + 128];
    __syncthreads();

    if (blockIdx.x < B_N) {
        // ---- squared distance ----
        int b = blockIdx.x;
        int c = lab[b];
        v4f xv = ((const v4f*)(x + (size_t)b * D_N))[t];
        v4f cv = ((const v4f*)(centers + (size_t)c * D_N))[t];
        v4f d = xv - cv;
        float s = d[0] * d[0] + d[1] * d[1] + d[2] * d[2] + d[3] * d[3];
#pragma unroll
        for (int off = 32; off > 0; off >>= 1) s += __shfl_down(s, off, 64);
        if ((t & 63) == 0) ws[t >> 6] = s;
        __syncthreads();
        if (t == 0) result[b] = ws[0] + ws[1];
    } else {
        // ---- touched-row fixup ----
        int b = blockIdx.x - B_N;
        int c = lab[b];
        for (int i = 0; i < b; ++i)
            if (lab[i] == c) return;             // not first occurrence: done
        int n = 0;
        v4f sx = {0.f, 0.f, 0.f, 0.f};
        for (int i = 0; i < B_N; ++i) {
            if (lab[i] == c) {                   // wave-uniform branch
                ++n;
                sx += ((const v4f*)(x + (size_t)i * D_N))[t];
            }
        }
        float inv = 1.0f / (float)(n + 1);
        float ac = 1.0f - ALPHA * (float)n * inv;
        float bc = ALPHA * inv;
        v4f cv = ((const v4f*)(centers + (size_t)c * D_N))[t];
        v4f res = cv * ac + sx * bc;
        ((v4f*)(newc + (size_t)c * D_N))[t] = res;
    }
}

extern "C" void kernel_launch(void* const* d_in, const int* in_sizes, int n_in,
                              void* d_out, int out_size, void* d_ws, size_t ws_size,
                              hipStream_t stream) {
    const float* x       = (const float*)d_in[0];   // [B, D]
    const float* onehot  = (const float*)d_in[1];   // [B, C]
    const float* centers = (const float*)d_in[2];   // [C, D]
    float* out    = (float*)d_out;
    float* result = out;                            // [B, 1] -> 256 floats
    float* newc   = out + B_N;                      // [C, D], 16B-aligned (1 KB offset)

    int* labels = (int*)d_ws;                       // B ints (1 KB of workspace)

    scan_copy<<<2048, 256, 0, stream>>>(onehot, (const v4f*)centers,
                                        (v4f*)newc, labels);
    finish<<<512, 128, 0, stream>>>(x, centers, labels, result, newc);
}